// Round 4
// baseline (77.304 us; speedup 1.0000x reference)
//
#include <hip/hip_runtime.h>
#include <stdint.h>

// WildCatPool: per (b,c) row of n=112*112=12544 fp32, mean of top kmax=6272.
// 6400 rows, one block (256 thr) per row. Keys in registers. 2-level radix
// select (13 bits + 10 bits) resolving the threshold to a 512-wide key bin;
// remaining krem elements approximated by the bin mean (relative bin spread
// 2^-14 -> error ~1e-9 on this data, tolerance is 1.68e-2). No compaction,
// no level 2. Histogram zeroing vectorized uint4.

constexpr int N_ELEM = 112 * 112;            // 12544 = 256*49
constexpr int KMAX   = 6272;
constexpr int NT     = 256;                  // 4 waves
constexpr int PER    = 49;
constexpr int NBIN0  = 8192;                 // 13-bit level 0
constexpr int H0W    = NBIN0 + (NBIN0 >> 5); // 8448 padded words (33 KB)
constexpr int H1W    = 1024 + 32;            // 1056 padded words (aliased low)

// order-preserving float -> uint key (larger float => larger key)
__device__ __forceinline__ unsigned int f2key(float f) {
    unsigned int u = __float_as_uint(f);
    return u ^ ((unsigned int)(((int)u) >> 31) | 0x80000000u);
}
__device__ __forceinline__ float key2f(unsigned int k) {
    unsigned int u = (k & 0x80000000u) ? (k ^ 0x80000000u) : ~k;
    return __uint_as_float(u);
}
// padded histogram address: one pad word per 32 bins -> conflict-free scans
__device__ __forceinline__ int hidx(int bin) { return bin + (bin >> 5); }

// Find bin containing the krem-th largest over BPT*256 bins (padded layout).
// s_sel[0]=bin, s_sel[1]=count strictly above that bin. Ends synced.
template<int BPT>
__device__ __forceinline__ void pick_bin(const unsigned int* hist, unsigned int krem,
                                         int t, unsigned int* s_sel,
                                         unsigned int* s_wsum) {
    const int lane = t & 63, w = t >> 6;
    const int base = hidx(BPT * t);
    unsigned int local = 0;
    #pragma unroll
    for (int b = 0; b < BPT; ++b) local += hist[base + b];
    unsigned int suf = local;
    #pragma unroll
    for (int d = 1; d < 64; d <<= 1) {
        unsigned int v = __shfl_down(suf, d);
        if (lane + d < 64) suf += v;
    }
    if (lane == 0) s_wsum[w] = suf;
    __syncthreads();
    unsigned int suf_all = suf;
    #pragma unroll
    for (int ww = 0; ww < 4; ++ww) if (ww > w) suf_all += s_wsum[ww];
    unsigned int above = suf_all - local;
    if (above < krem && krem <= suf_all) {   // unique crossing thread
        unsigned int c = above;
        #pragma unroll
        for (int b = BPT - 1; b >= 0; --b) {
            unsigned int h = hist[base + b];
            if (c + h >= krem) { s_sel[0] = (unsigned int)(BPT * t + b); s_sel[1] = c; break; }
            c += h;
        }
    }
    __syncthreads();
}

__global__ __launch_bounds__(NT, 4)
void wildcat_topk_kernel(const float* __restrict__ x, float* __restrict__ out) {
    __shared__ __align__(16) unsigned int hist[H0W];   // 33 KB
    __shared__ unsigned int s_sel[2];
    __shared__ unsigned int s_wsum[4];
    __shared__ float s_part[8];

    const int row = blockIdx.x;
    const int t   = threadIdx.x;
    const float* src = x + (size_t)row * N_ELEM;

    // ---- load row into registers as monotone keys (coalesced float4) ----
    unsigned int key[PER];
    const float4* src4 = (const float4*)src;
    #pragma unroll
    for (int j = 0; j < 12; ++j) {
        float4 v = src4[t + NT * j];
        key[4 * j + 0] = f2key(v.x);
        key[4 * j + 1] = f2key(v.y);
        key[4 * j + 2] = f2key(v.z);
        key[4 * j + 3] = f2key(v.w);
    }
    key[48] = f2key(src[12288 + t]);

    // ---- zero level-0 histogram (vectorized) ----
    uint4* h4 = (uint4*)hist;
    for (int i = t; i < H0W / 4; i += NT) h4[i] = make_uint4(0, 0, 0, 0);
    __syncthreads();

    // ---- level 0: bits [31:19], 8192 bins ----
    #pragma unroll
    for (int j = 0; j < PER; ++j)
        atomicAdd(&hist[hidx(key[j] >> 19)], 1u);
    __syncthreads();

    pick_bin<32>(hist, KMAX, t, s_sel, s_wsum);
    const unsigned int sel0 = s_sel[0];
    unsigned int krem = KMAX - s_sel[1];
    __syncthreads();   // reads of hist done before re-zero

    // ---- zero level-1 histogram region (low 1056 words) ----
    for (int i = t; i < H1W / 4; i += NT) h4[i] = make_uint4(0, 0, 0, 0);
    __syncthreads();

    // ---- level 1: bits [18:9], 1024 bins, over register keys ----
    #pragma unroll
    for (int j = 0; j < PER; ++j)
        if ((key[j] >> 19) == sel0)
            atomicAdd(&hist[hidx((key[j] >> 9) & 1023u)], 1u);
    __syncthreads();

    pick_bin<4>(hist, krem, t, s_sel, s_wsum);
    const unsigned int sel1 = s_sel[0];
    krem -= s_sel[1];                              // needed from inside the bin
    const unsigned int cnt_bin = hist[hidx(sel1)]; // elements in the bin (>= krem)
    const unsigned int p219 = (sel0 << 10) | sel1; // bits [31:9] of threshold

    // ---- final register pass: exact sum above bin + bin sum ----
    float sum_hi = 0.f, sum_bin = 0.f;
    #pragma unroll
    for (int j = 0; j < PER; ++j) {
        unsigned int k = key[j];
        unsigned int hi23 = k >> 9;
        if (hi23 > p219)       sum_hi  += key2f(k);
        else if (hi23 == p219) sum_bin += key2f(k);
    }
    #pragma unroll
    for (int d = 1; d < 64; d <<= 1) {
        sum_hi  += __shfl_xor(sum_hi, d);
        sum_bin += __shfl_xor(sum_bin, d);
    }
    if ((t & 63) == 0) { s_part[t >> 6] = sum_hi; s_part[4 + (t >> 6)] = sum_bin; }
    __syncthreads();

    if (t == 0) {
        float hi  = s_part[0] + s_part[1] + s_part[2] + s_part[3];
        float bin = s_part[4] + s_part[5] + s_part[6] + s_part[7];
        // krem elements from the bin, approximated by the bin mean
        // (bin spread is 2^-14 relative -> negligible vs 1.68e-2 tolerance)
        out[row] = (hi + (float)krem * (bin / (float)cnt_bin)) / (float)KMAX;
    }
}

extern "C" void kernel_launch(void* const* d_in, const int* in_sizes, int n_in,
                              void* d_out, int out_size, void* d_ws, size_t ws_size,
                              hipStream_t stream) {
    const float* x = (const float*)d_in[0];
    float* out = (float*)d_out;
    const int rows = out_size;  // 6400
    wildcat_topk_kernel<<<rows, NT, 0, stream>>>(x, out);
}